// Round 1
// baseline (3833.101 us; speedup 1.0000x reference)
//
#include <hip/hip_runtime.h>
#include <hip/hip_bf16.h>

#define N_NODES 100000
#define N_EDGES 1600000
#define N_GRAPH 1024
#define DIM_BASE 1000
#define DIM_AUG 384
#define DIM_IN 1384
#define HD 256
#define BN_EPS 1e-5f

// ---------------- utility ----------------
__global__ void zero_kernel(unsigned int* __restrict__ p, int n) {
    int i = blockIdx.x * blockDim.x + threadIdx.x;
    if (i < n) p[i] = 0u;
}

// ---------------- graph prep ----------------
__global__ void count_edges_kernel(const int* __restrict__ dst, int* __restrict__ counts, int e) {
    int i = blockIdx.x * blockDim.x + threadIdx.x;
    if (i < e) atomicAdd(&counts[dst[i]], 1);
}

__global__ __launch_bounds__(1024) void scan_kernel(const int* __restrict__ counts,
                                                    int* __restrict__ row_ptr,
                                                    int* __restrict__ cursor,
                                                    float* __restrict__ dinv, int n) {
    __shared__ int sh[1024];
    int tid = threadIdx.x;
    int chunk = (n + 1023) >> 10;
    int start = tid * chunk;
    int end = min(start + chunk, n);
    int s = 0;
    for (int i = start; i < end; ++i) s += counts[i];
    sh[tid] = s;
    __syncthreads();
    for (int off = 1; off < 1024; off <<= 1) {
        int v = (tid >= off) ? sh[tid - off] : 0;
        __syncthreads();
        sh[tid] += v;
        __syncthreads();
    }
    int run = sh[tid] - s;  // exclusive prefix
    for (int i = start; i < end; ++i) {
        row_ptr[i] = run;
        cursor[i] = run;
        run += counts[i];
        dinv[i] = rsqrtf((float)counts[i] + 1.0f);
    }
    if (start < n && end == n) row_ptr[n] = run;
}

__global__ void fill_edges_kernel(const int* __restrict__ src, const int* __restrict__ dst,
                                  int* __restrict__ cursor, int* __restrict__ col, int e) {
    int i = blockIdx.x * blockDim.x + threadIdx.x;
    if (i < e) {
        int pos = atomicAdd(&cursor[dst[i]], 1);
        col[pos] = src[i];
    }
}

// ---------------- fusion GEMM: C = relu(concat(x, xa) @ B + bias), [M x 1384]@[1384 x 256] ----------------
__global__ __launch_bounds__(256) void fusion_gemm_kernel(
        const float* __restrict__ x, const float* __restrict__ xa,
        const float* __restrict__ B, const float* __restrict__ bias,
        float* __restrict__ C, int M) {
    __shared__ float As[16][68];
    __shared__ float Bs[16][HD];
    int tid = threadIdx.x;
    int tx = tid & 31, ty = tid >> 5;
    int row0 = blockIdx.x * 64;
    float acc[8][8];
#pragma unroll
    for (int i = 0; i < 8; ++i)
#pragma unroll
        for (int j = 0; j < 8; ++j) acc[i][j] = 0.f;

    int kk = tid & 15, mbase = tid >> 4;
    for (int k0 = 0; k0 < DIM_IN; k0 += 16) {
#pragma unroll
        for (int p = 0; p < 4; ++p) {
            int mm = mbase + p * 16;
            int r = row0 + mm, kg = k0 + kk;
            float v = 0.f;
            if (r < M && kg < DIM_IN)
                v = (kg < DIM_BASE) ? x[(size_t)r * DIM_BASE + kg]
                                    : xa[(size_t)r * DIM_AUG + (kg - DIM_BASE)];
            As[kk][mm] = v;
        }
#pragma unroll
        for (int q = 0; q < 16; ++q) {
            int kg = k0 + q;
            Bs[q][tid] = (kg < DIM_IN) ? B[(size_t)kg * HD + tid] : 0.f;
        }
        __syncthreads();
#pragma unroll
        for (int q = 0; q < 16; ++q) {
            float a[8], b[8];
#pragma unroll
            for (int i = 0; i < 8; ++i) a[i] = As[q][ty * 8 + i];
#pragma unroll
            for (int j = 0; j < 8; ++j) b[j] = Bs[q][tx + 32 * j];
#pragma unroll
            for (int i = 0; i < 8; ++i)
#pragma unroll
                for (int j = 0; j < 8; ++j) acc[i][j] = fmaf(a[i], b[j], acc[i][j]);
        }
        __syncthreads();
    }
#pragma unroll
    for (int i = 0; i < 8; ++i) {
        int r = row0 + ty * 8 + i;
        if (r < M) {
#pragma unroll
            for (int j = 0; j < 8; ++j) {
                int c = tx + 32 * j;
                C[(size_t)r * HD + c] = fmaxf(acc[i][j] + bias[c], 0.f);
            }
        }
    }
}

// ---------------- layer GEMM: C = A' @ B, A' = A (bnp==null) or relu(A*scale+shift) ----------------
__global__ __launch_bounds__(256) void gemm_h_kernel(
        const float* __restrict__ A, const float* __restrict__ B,
        const float* __restrict__ bnp,  // null or [512] {scale, shift}
        float* __restrict__ C, int M) {
    __shared__ float As[16][68];
    __shared__ float Bs[16][HD];
    int tid = threadIdx.x;
    int tx = tid & 31, ty = tid >> 5;
    int row0 = blockIdx.x * 64;
    float acc[8][8];
#pragma unroll
    for (int i = 0; i < 8; ++i)
#pragma unroll
        for (int j = 0; j < 8; ++j) acc[i][j] = 0.f;

    int kk = tid & 15, mbase = tid >> 4;
    for (int k0 = 0; k0 < HD; k0 += 16) {
#pragma unroll
        for (int p = 0; p < 4; ++p) {
            int mm = mbase + p * 16;
            int r = row0 + mm, kg = k0 + kk;
            float v = (r < M) ? A[(size_t)r * HD + kg] : 0.f;
            if (bnp) v = fmaxf(fmaf(v, bnp[kg], bnp[HD + kg]), 0.f);
            As[kk][mm] = v;
        }
#pragma unroll
        for (int q = 0; q < 16; ++q) {
            Bs[q][tid] = B[(size_t)(k0 + q) * HD + tid];
        }
        __syncthreads();
#pragma unroll
        for (int q = 0; q < 16; ++q) {
            float a[8], b[8];
#pragma unroll
            for (int i = 0; i < 8; ++i) a[i] = As[q][ty * 8 + i];
#pragma unroll
            for (int j = 0; j < 8; ++j) b[j] = Bs[q][tx + 32 * j];
#pragma unroll
            for (int i = 0; i < 8; ++i)
#pragma unroll
                for (int j = 0; j < 8; ++j) acc[i][j] = fmaf(a[i], b[j], acc[i][j]);
        }
        __syncthreads();
    }
#pragma unroll
    for (int i = 0; i < 8; ++i) {
        int r = row0 + ty * 8 + i;
        if (r < M) {
#pragma unroll
            for (int j = 0; j < 8; ++j) {
                C[(size_t)r * HD + tx + 32 * j] = acc[i][j];
            }
        }
    }
}

// ---------------- GCN aggregation: out[i] = sum_{e:dst=i} t[src]*dinv[src]*dinv[i] + t[i]*dinv[i]^2 + b ----------------
__global__ __launch_bounds__(256) void agg_kernel(
        const float* __restrict__ t, const float* __restrict__ dinv,
        const int* __restrict__ row_ptr, const int* __restrict__ col,
        const float* __restrict__ bias, float* __restrict__ outp, int n) {
    int i = blockIdx.x;
    int tid = threadIdx.x;
    float di = dinv[i];
    float acc = t[(size_t)i * HD + tid] * di * di;
    int e = row_ptr[i], end = row_ptr[i + 1];
    for (; e + 1 < end; e += 2) {
        int s0 = col[e], s1 = col[e + 1];
        float w0 = dinv[s0] * di, w1 = dinv[s1] * di;
        float v0 = t[(size_t)s0 * HD + tid];
        float v1 = t[(size_t)s1 * HD + tid];
        acc = fmaf(v0, w0, acc);
        acc = fmaf(v1, w1, acc);
    }
    if (e < end) {
        int s0 = col[e];
        acc = fmaf(t[(size_t)s0 * HD + tid], dinv[s0] * di, acc);
    }
    outp[(size_t)i * HD + tid] = acc + bias[tid];
}

// ---------------- BatchNorm stats (column sums) ----------------
__global__ __launch_bounds__(256) void bn_stats_kernel(const float* __restrict__ a,
                                                       float* __restrict__ sums, int n) {
    int tid = threadIdx.x;
    int r0 = blockIdx.x * 256;
    int r1 = min(r0 + 256, n);
    float s = 0.f, s2 = 0.f;
    for (int r = r0; r < r1; ++r) {
        float v = a[(size_t)r * HD + tid];
        s += v;
        s2 = fmaf(v, v, s2);
    }
    atomicAdd(&sums[tid], s);
    atomicAdd(&sums[HD + tid], s2);
}

__global__ __launch_bounds__(256) void bn_final_kernel(const float* __restrict__ sums,
                                                       const float* __restrict__ g,
                                                       const float* __restrict__ be,
                                                       float* __restrict__ p, int n) {
    int tid = threadIdx.x;
    float mean = sums[tid] / (float)n;
    float var = sums[HD + tid] / (float)n - mean * mean;
    float sc = g[tid] * rsqrtf(var + BN_EPS);
    p[tid] = sc;
    p[HD + tid] = be[tid] - mean * sc;
}

// ---------------- graph sizes ----------------
__global__ void graph_cnt_kernel(const int* __restrict__ batch, float* __restrict__ cnt, int n) {
    int i = blockIdx.x * blockDim.x + threadIdx.x;
    if (i < n) atomicAdd(&cnt[batch[i]], 1.0f);
}

// ---------------- BN2 apply + relu + mean-pool accumulate (batch is sorted) ----------------
__global__ __launch_bounds__(256) void bn_relu_pool_kernel(const float* __restrict__ a,
                                                           const float* __restrict__ p,
                                                           const int* __restrict__ batch,
                                                           float* __restrict__ pooled, int n) {
    int tid = threadIdx.x;
    int n0 = blockIdx.x * 64;
    int n1 = min(n0 + 64, n);
    if (n0 >= n) return;
    float sc = p[tid], sh = p[HD + tid];
    int curg = batch[n0];
    float acc = 0.f;
    for (int i = n0; i < n1; ++i) {
        int g = batch[i];
        if (g != curg) {
            atomicAdd(&pooled[(size_t)curg * HD + tid], acc);
            acc = 0.f;
            curg = g;
        }
        acc += fmaxf(fmaf(a[(size_t)i * HD + tid], sc, sh), 0.f);
    }
    atomicAdd(&pooled[(size_t)curg * HD + tid], acc);
}

// ---------------- head: (pooled/cnt) @ fcW + fcb -> log_softmax ----------------
__global__ __launch_bounds__(64) void head_kernel(const float* __restrict__ pooled,
                                                  const float* __restrict__ cnt,
                                                  const float* __restrict__ fcW,
                                                  const float* __restrict__ fcb,
                                                  float* __restrict__ outp) {
    int g = blockIdx.x, lane = threadIdx.x;
    float inv = 1.0f / fmaxf(cnt[g], 1.0f);
    float a0 = 0.f, a1 = 0.f;
    for (int j = lane; j < HD; j += 64) {
        float v = pooled[(size_t)g * HD + j] * inv;
        a0 = fmaf(v, fcW[j * 2 + 0], a0);
        a1 = fmaf(v, fcW[j * 2 + 1], a1);
    }
    for (int off = 32; off > 0; off >>= 1) {
        a0 += __shfl_down(a0, off);
        a1 += __shfl_down(a1, off);
    }
    if (lane == 0) {
        float l0 = a0 + fcb[0], l1 = a1 + fcb[1];
        float m = fmaxf(l0, l1);
        float lse = m + logf(expf(l0 - m) + expf(l1 - m));
        outp[g * 2 + 0] = l0 - lse;
        outp[g * 2 + 1] = l1 - lse;
    }
}

extern "C" void kernel_launch(void* const* d_in, const int* in_sizes, int n_in,
                              void* d_out, int out_size, void* d_ws, size_t ws_size,
                              hipStream_t stream) {
    const float* x        = (const float*)d_in[0];
    const float* x_aug    = (const float*)d_in[1];
    const float* fusion_W = (const float*)d_in[2];
    const float* fusion_b = (const float*)d_in[3];
    const float* W0       = (const float*)d_in[4];
    const float* b0       = (const float*)d_in[5];
    const float* g0       = (const float*)d_in[6];
    const float* be0      = (const float*)d_in[7];
    const float* W1       = (const float*)d_in[8];
    const float* b1       = (const float*)d_in[9];
    const float* g1       = (const float*)d_in[10];
    const float* be1      = (const float*)d_in[11];
    const float* fc_W     = (const float*)d_in[12];
    const float* fc_b     = (const float*)d_in[13];
    const int*   eidx     = (const int*)d_in[14];
    const int*   batch    = (const int*)d_in[15];
    float* outp = (float*)d_out;

    const int N = N_NODES, E = N_EDGES, G = N_GRAPH;
    const int* src = eidx;
    const int* dst = eidx + E;

    // workspace layout
    size_t off = 0;
    char* ws = (char*)d_ws;
    auto take = [&](size_t nbytes) -> void* {
        void* p = ws + off;
        off = (off + nbytes + 255) & ~(size_t)255;
        return p;
    };
    float* bufA    = (float*)take((size_t)N * HD * 4);
    float* bufB    = (float*)take((size_t)N * HD * 4);
    float* dinv    = (float*)take((size_t)N * 4);
    int*   row_ptr = (int*)take((size_t)(N + 1) * 4);
    int*   cursor  = (int*)take((size_t)N * 4);
    int*   col     = (int*)take((size_t)E * 4);
    float* bn1p    = (float*)take(512 * 4);
    float* bn2p    = (float*)take(512 * 4);
    // contiguous zero region
    size_t zwords = (size_t)N + 512 + 512 + (size_t)G * HD + G;
    unsigned int* zbase = (unsigned int*)take(zwords * 4);
    int*   counts = (int*)zbase;
    float* bn1s   = (float*)(zbase + N);
    float* bn2s   = bn1s + 512;
    float* pooled = bn2s + 512;
    float* cnt    = pooled + (size_t)G * HD;

    // 1. zero scratch accumulators
    zero_kernel<<<(int)((zwords + 255) / 256), 256, 0, stream>>>(zbase, (int)zwords);
    // 2. degree histogram
    count_edges_kernel<<<(E + 255) / 256, 256, 0, stream>>>(dst, counts, E);
    // 3. prefix sum -> CSR row_ptr, cursor, dinv
    scan_kernel<<<1, 1024, 0, stream>>>(counts, row_ptr, cursor, dinv, N);
    // 4. fill CSR columns
    fill_edges_kernel<<<(E + 255) / 256, 256, 0, stream>>>(src, dst, cursor, col, E);
    // 5. fusion GEMM + relu -> bufA (h0)
    fusion_gemm_kernel<<<(N + 63) / 64, 256, 0, stream>>>(x, x_aug, fusion_W, fusion_b, bufA, N);
    // 6. t1 = h0 @ W0 -> bufB
    gemm_h_kernel<<<(N + 63) / 64, 256, 0, stream>>>(bufA, W0, nullptr, bufB, N);
    // 7. aggregate -> bufA (+b0)
    agg_kernel<<<N, 256, 0, stream>>>(bufB, dinv, row_ptr, col, b0, bufA, N);
    // 8. BN1 stats
    bn_stats_kernel<<<(N + 255) / 256, 256, 0, stream>>>(bufA, bn1s, N);
    // 9. BN1 finalize
    bn_final_kernel<<<1, 256, 0, stream>>>(bn1s, g0, be0, bn1p, N);
    // 10. t2 = relu(bn1(bufA)) @ W1 -> bufB   (BN apply fused into A-load)
    gemm_h_kernel<<<(N + 63) / 64, 256, 0, stream>>>(bufA, W1, bn1p, bufB, N);
    // 11. aggregate -> bufA (+b1)
    agg_kernel<<<N, 256, 0, stream>>>(bufB, dinv, row_ptr, col, b1, bufA, N);
    // 12. BN2 stats
    bn_stats_kernel<<<(N + 255) / 256, 256, 0, stream>>>(bufA, bn2s, N);
    // 13. BN2 finalize
    bn_final_kernel<<<1, 256, 0, stream>>>(bn2s, g1, be1, bn2p, N);
    // 14. graph node counts
    graph_cnt_kernel<<<(N + 255) / 256, 256, 0, stream>>>(batch, cnt, N);
    // 15. BN2 apply + relu + pooled sums
    bn_relu_pool_kernel<<<(N + 63) / 64, 256, 0, stream>>>(bufA, bn2p, batch, pooled, N);
    // 16. head
    head_kernel<<<G, 64, 0, stream>>>(pooled, cnt, fc_W, fc_b, outp);
}

// Round 2
// 1549.332 us; speedup vs baseline: 2.4740x; 2.4740x over previous
//
#include <hip/hip_runtime.h>
#include <hip/hip_bf16.h>

#define N_NODES 100000
#define N_EDGES 1600000
#define N_GRAPH 1024
#define DIM_BASE 1000
#define DIM_AUG 384
#define DIM_IN 1384
#define KPAD_IN 1408
#define HD 256
#define BN_EPS 1e-5f

typedef _Float16 f16x8 __attribute__((ext_vector_type(8)));
typedef float f32x4 __attribute__((ext_vector_type(4)));

// ---------------- utility ----------------
__global__ void zero_kernel(unsigned int* __restrict__ p, int n) {
    int i = blockIdx.x * blockDim.x + threadIdx.x;
    if (i < n) p[i] = 0u;
}

// ---------------- graph prep ----------------
__global__ void count_edges_kernel(const int* __restrict__ dst, int* __restrict__ counts, int e) {
    int i = blockIdx.x * blockDim.x + threadIdx.x;
    if (i < e) atomicAdd(&counts[dst[i]], 1);
}

__global__ __launch_bounds__(1024) void scan_kernel(const int* __restrict__ counts,
                                                    int* __restrict__ row_ptr,
                                                    int* __restrict__ cursor,
                                                    float* __restrict__ dinv, int n) {
    __shared__ int sh[1024];
    int tid = threadIdx.x;
    int chunk = (n + 1023) >> 10;
    int start = tid * chunk;
    int end = min(start + chunk, n);
    int s = 0;
    for (int i = start; i < end; ++i) s += counts[i];
    sh[tid] = s;
    __syncthreads();
    for (int off = 1; off < 1024; off <<= 1) {
        int v = (tid >= off) ? sh[tid - off] : 0;
        __syncthreads();
        sh[tid] += v;
        __syncthreads();
    }
    int run = sh[tid] - s;  // exclusive prefix
    for (int i = start; i < end; ++i) {
        row_ptr[i] = run;
        cursor[i] = run;
        run += counts[i];
        dinv[i] = rsqrtf((float)counts[i] + 1.0f);
    }
    if (start < n && end == n) row_ptr[n] = run;
}

__global__ void fill_edges_kernel(const int* __restrict__ src, const int* __restrict__ dst,
                                  int* __restrict__ cursor, int* __restrict__ col, int e) {
    int i = blockIdx.x * blockDim.x + threadIdx.x;
    if (i < e) {
        int pos = atomicAdd(&cursor[dst[i]], 1);
        col[pos] = src[i];
    }
}

// ---------------- B pre-transpose to fragment-ready f16 chunks ----------------
// Bt chunk index (k>>3)*256 + col holds f16x8 { W[k+j][col] : j=0..7 }, zero-padded past K.
__global__ __launch_bounds__(256) void btrans_kernel(const float* __restrict__ W,
                                                     f16x8* __restrict__ Bt,
                                                     int K, int nchunks) {
    int idx = blockIdx.x * 256 + threadIdx.x;
    if (idx >= nchunks) return;
    int col = idx & 255;
    int kbase = (idx >> 8) * 8;
    f16x8 h;
#pragma unroll
    for (int j = 0; j < 8; ++j) {
        int k = kbase + j;
        float v = (k < K) ? W[(size_t)k * HD + col] : 0.f;
        h[j] = (_Float16)v;
    }
    Bt[idx] = h;
}

// ---------------- fusion GEMM (MFMA): C = relu(concat(x,xa) @ W + bias) ----------------
// block: 512 thr = 8 waves (2x4), tile 128x256, BK=32
__global__ __launch_bounds__(512, 4) void fusion_mfma_kernel(
        const float* __restrict__ x, const float* __restrict__ xa,
        const f16x8* __restrict__ Bt, const float* __restrict__ bias,
        float* __restrict__ C, int M) {
    __shared__ _Float16 Al[128 * 40];
    __shared__ _Float16 Bl[32 * 256];
    int tid = threadIdx.x;
    int lane = tid & 63;
    int wid = tid >> 6;
    int wr = wid >> 2, wc = wid & 3;
    int l16 = lane & 15, l4 = lane >> 4;
    int row0 = blockIdx.x * 128;

    f32x4 acc[4][4];
#pragma unroll
    for (int m = 0; m < 4; ++m)
#pragma unroll
        for (int n = 0; n < 4; ++n) acc[m][n] = (f32x4){0.f, 0.f, 0.f, 0.f};

    int arow = tid >> 2;        // 0..127
    int akq = (tid & 3) * 8;    // 0,8,16,24
    int ar = row0 + arow;

    const int S = KPAD_IN / 32;  // 44
    for (int s = 0; s < S; ++s) {
        int kg = s * 32 + akq;
        // global loads (overlap with previous iter's MFMA)
        float fv[8];
#pragma unroll
        for (int j = 0; j < 8; ++j) fv[j] = 0.f;
        if (ar < M && kg < DIM_IN) {
            // 1000 and 1384 are multiples of 8: the 8-span never straddles x/xa or the K tail
            const float* sp = (kg < DIM_BASE) ? (x + (size_t)ar * DIM_BASE + kg)
                                              : (xa + (size_t)ar * DIM_AUG + (kg - DIM_BASE));
            float4 v0 = ((const float4*)sp)[0];
            float4 v1 = ((const float4*)sp)[1];
            fv[0] = v0.x; fv[1] = v0.y; fv[2] = v0.z; fv[3] = v0.w;
            fv[4] = v1.x; fv[5] = v1.y; fv[6] = v1.z; fv[7] = v1.w;
        }
        f16x8 av;
#pragma unroll
        for (int j = 0; j < 8; ++j) av[j] = (_Float16)fv[j];
        f16x8 bv0 = Bt[(size_t)s * 1024 + tid];
        f16x8 bv1 = Bt[(size_t)s * 1024 + 512 + tid];

        __syncthreads();  // previous tile fully consumed
        *(f16x8*)&Al[arow * 40 + akq] = av;
        *(f16x8*)&Bl[(size_t)tid * 8] = bv0;
        *(f16x8*)&Bl[(size_t)(512 + tid) * 8] = bv1;
        __syncthreads();  // tile visible

        f16x8 bf[4];
#pragma unroll
        for (int n = 0; n < 4; ++n)
            bf[n] = *(const f16x8*)&Bl[(size_t)(l4 * 256 + wc * 64 + n * 16 + l16) * 8];
#pragma unroll
        for (int m = 0; m < 4; ++m) {
            f16x8 af = *(const f16x8*)&Al[(size_t)(wr * 64 + m * 16 + l16) * 40 + l4 * 8];
#pragma unroll
            for (int n = 0; n < 4; ++n)
                acc[m][n] = __builtin_amdgcn_mfma_f32_16x16x32_f16(af, bf[n], acc[m][n], 0, 0, 0);
        }
    }

#pragma unroll
    for (int n = 0; n < 4; ++n) {
        int colF = wc * 64 + n * 16 + l16;
        float bcol = bias[colF];
#pragma unroll
        for (int m = 0; m < 4; ++m) {
#pragma unroll
            for (int r = 0; r < 4; ++r) {
                int rowF = row0 + wr * 64 + m * 16 + l4 * 4 + r;
                if (rowF < M)
                    C[(size_t)rowF * HD + colF] = fmaxf(acc[m][n][r] + bcol, 0.f);
            }
        }
    }
}

// ---------------- H-GEMM (MFMA): C = A' @ W, A' = A or relu(A*scale+shift) ----------------
__global__ __launch_bounds__(512, 4) void hgemm_mfma_kernel(
        const float* __restrict__ A, const f16x8* __restrict__ Bt,
        const float* __restrict__ bnp,  // null or [512] {scale, shift}
        float* __restrict__ C, int M) {
    __shared__ _Float16 Al[128 * 40];
    __shared__ _Float16 Bl[32 * 256];
    __shared__ float bns[512];
    int tid = threadIdx.x;
    int lane = tid & 63;
    int wid = tid >> 6;
    int wr = wid >> 2, wc = wid & 3;
    int l16 = lane & 15, l4 = lane >> 4;
    int row0 = blockIdx.x * 128;

    if (bnp) bns[tid] = bnp[tid];

    f32x4 acc[4][4];
#pragma unroll
    for (int m = 0; m < 4; ++m)
#pragma unroll
        for (int n = 0; n < 4; ++n) acc[m][n] = (f32x4){0.f, 0.f, 0.f, 0.f};

    int arow = tid >> 2;
    int akq = (tid & 3) * 8;
    int ar = row0 + arow;

    __syncthreads();  // bns visible

    const int S = HD / 32;  // 8
    for (int s = 0; s < S; ++s) {
        int kg = s * 32 + akq;
        float fv[8];
#pragma unroll
        for (int j = 0; j < 8; ++j) fv[j] = 0.f;
        if (ar < M) {
            const float* sp = A + (size_t)ar * HD + kg;
            float4 v0 = ((const float4*)sp)[0];
            float4 v1 = ((const float4*)sp)[1];
            fv[0] = v0.x; fv[1] = v0.y; fv[2] = v0.z; fv[3] = v0.w;
            fv[4] = v1.x; fv[5] = v1.y; fv[6] = v1.z; fv[7] = v1.w;
        }
        if (bnp) {
#pragma unroll
            for (int j = 0; j < 8; ++j)
                fv[j] = fmaxf(fmaf(fv[j], bns[kg + j], bns[HD + kg + j]), 0.f);
        }
        f16x8 av;
#pragma unroll
        for (int j = 0; j < 8; ++j) av[j] = (_Float16)fv[j];
        f16x8 bv0 = Bt[(size_t)s * 1024 + tid];
        f16x8 bv1 = Bt[(size_t)s * 1024 + 512 + tid];

        __syncthreads();
        *(f16x8*)&Al[arow * 40 + akq] = av;
        *(f16x8*)&Bl[(size_t)tid * 8] = bv0;
        *(f16x8*)&Bl[(size_t)(512 + tid) * 8] = bv1;
        __syncthreads();

        f16x8 bf[4];
#pragma unroll
        for (int n = 0; n < 4; ++n)
            bf[n] = *(const f16x8*)&Bl[(size_t)(l4 * 256 + wc * 64 + n * 16 + l16) * 8];
#pragma unroll
        for (int m = 0; m < 4; ++m) {
            f16x8 af = *(const f16x8*)&Al[(size_t)(wr * 64 + m * 16 + l16) * 40 + l4 * 8];
#pragma unroll
            for (int n = 0; n < 4; ++n)
                acc[m][n] = __builtin_amdgcn_mfma_f32_16x16x32_f16(af, bf[n], acc[m][n], 0, 0, 0);
        }
    }

#pragma unroll
    for (int n = 0; n < 4; ++n) {
        int colF = wc * 64 + n * 16 + l16;
#pragma unroll
        for (int m = 0; m < 4; ++m) {
#pragma unroll
            for (int r = 0; r < 4; ++r) {
                int rowF = row0 + wr * 64 + m * 16 + l4 * 4 + r;
                if (rowF < M)
                    C[(size_t)rowF * HD + colF] = acc[m][n][r];
            }
        }
    }
}

// ---------------- GCN aggregation ----------------
__global__ __launch_bounds__(256) void agg_kernel(
        const float* __restrict__ t, const float* __restrict__ dinv,
        const int* __restrict__ row_ptr, const int* __restrict__ col,
        const float* __restrict__ bias, float* __restrict__ outp, int n) {
    int i = blockIdx.x;
    int tid = threadIdx.x;
    float di = dinv[i];
    float acc = t[(size_t)i * HD + tid] * di * di;
    int e = row_ptr[i], end = row_ptr[i + 1];
    for (; e + 1 < end; e += 2) {
        int s0 = col[e], s1 = col[e + 1];
        float w0 = dinv[s0] * di, w1 = dinv[s1] * di;
        float v0 = t[(size_t)s0 * HD + tid];
        float v1 = t[(size_t)s1 * HD + tid];
        acc = fmaf(v0, w0, acc);
        acc = fmaf(v1, w1, acc);
    }
    if (e < end) {
        int s0 = col[e];
        acc = fmaf(t[(size_t)s0 * HD + tid], dinv[s0] * di, acc);
    }
    outp[(size_t)i * HD + tid] = acc + bias[tid];
}

// ---------------- BatchNorm stats ----------------
__global__ __launch_bounds__(256) void bn_stats_kernel(const float* __restrict__ a,
                                                       float* __restrict__ sums, int n) {
    int tid = threadIdx.x;
    int r0 = blockIdx.x * 256;
    int r1 = min(r0 + 256, n);
    float s = 0.f, s2 = 0.f;
    for (int r = r0; r < r1; ++r) {
        float v = a[(size_t)r * HD + tid];
        s += v;
        s2 = fmaf(v, v, s2);
    }
    atomicAdd(&sums[tid], s);
    atomicAdd(&sums[HD + tid], s2);
}

__global__ __launch_bounds__(256) void bn_final_kernel(const float* __restrict__ sums,
                                                       const float* __restrict__ g,
                                                       const float* __restrict__ be,
                                                       float* __restrict__ p, int n) {
    int tid = threadIdx.x;
    float mean = sums[tid] / (float)n;
    float var = sums[HD + tid] / (float)n - mean * mean;
    float sc = g[tid] * rsqrtf(var + BN_EPS);
    p[tid] = sc;
    p[HD + tid] = be[tid] - mean * sc;
}

// ---------------- graph sizes ----------------
__global__ void graph_cnt_kernel(const int* __restrict__ batch, float* __restrict__ cnt, int n) {
    int i = blockIdx.x * blockDim.x + threadIdx.x;
    if (i < n) atomicAdd(&cnt[batch[i]], 1.0f);
}

// ---------------- BN2 apply + relu + mean-pool accumulate (batch sorted) ----------------
__global__ __launch_bounds__(256) void bn_relu_pool_kernel(const float* __restrict__ a,
                                                           const float* __restrict__ p,
                                                           const int* __restrict__ batch,
                                                           float* __restrict__ pooled, int n) {
    int tid = threadIdx.x;
    int n0 = blockIdx.x * 64;
    int n1 = min(n0 + 64, n);
    if (n0 >= n) return;
    float sc = p[tid], sh = p[HD + tid];
    int curg = batch[n0];
    float acc = 0.f;
    for (int i = n0; i < n1; ++i) {
        int g = batch[i];
        if (g != curg) {
            atomicAdd(&pooled[(size_t)curg * HD + tid], acc);
            acc = 0.f;
            curg = g;
        }
        acc += fmaxf(fmaf(a[(size_t)i * HD + tid], sc, sh), 0.f);
    }
    atomicAdd(&pooled[(size_t)curg * HD + tid], acc);
}

// ---------------- head ----------------
__global__ __launch_bounds__(64) void head_kernel(const float* __restrict__ pooled,
                                                  const float* __restrict__ cnt,
                                                  const float* __restrict__ fcW,
                                                  const float* __restrict__ fcb,
                                                  float* __restrict__ outp) {
    int g = blockIdx.x, lane = threadIdx.x;
    float inv = 1.0f / fmaxf(cnt[g], 1.0f);
    float a0 = 0.f, a1 = 0.f;
    for (int j = lane; j < HD; j += 64) {
        float v = pooled[(size_t)g * HD + j] * inv;
        a0 = fmaf(v, fcW[j * 2 + 0], a0);
        a1 = fmaf(v, fcW[j * 2 + 1], a1);
    }
    for (int off = 32; off > 0; off >>= 1) {
        a0 += __shfl_down(a0, off);
        a1 += __shfl_down(a1, off);
    }
    if (lane == 0) {
        float l0 = a0 + fcb[0], l1 = a1 + fcb[1];
        float m = fmaxf(l0, l1);
        float lse = m + logf(expf(l0 - m) + expf(l1 - m));
        outp[g * 2 + 0] = l0 - lse;
        outp[g * 2 + 1] = l1 - lse;
    }
}

extern "C" void kernel_launch(void* const* d_in, const int* in_sizes, int n_in,
                              void* d_out, int out_size, void* d_ws, size_t ws_size,
                              hipStream_t stream) {
    const float* x        = (const float*)d_in[0];
    const float* x_aug    = (const float*)d_in[1];
    const float* fusion_W = (const float*)d_in[2];
    const float* fusion_b = (const float*)d_in[3];
    const float* W0       = (const float*)d_in[4];
    const float* b0       = (const float*)d_in[5];
    const float* g0       = (const float*)d_in[6];
    const float* be0      = (const float*)d_in[7];
    const float* W1       = (const float*)d_in[8];
    const float* b1       = (const float*)d_in[9];
    const float* g1       = (const float*)d_in[10];
    const float* be1      = (const float*)d_in[11];
    const float* fc_W     = (const float*)d_in[12];
    const float* fc_b     = (const float*)d_in[13];
    const int*   eidx     = (const int*)d_in[14];
    const int*   batch    = (const int*)d_in[15];
    float* outp = (float*)d_out;

    const int N = N_NODES, E = N_EDGES, G = N_GRAPH;
    const int* src = eidx;
    const int* dst = eidx + E;

    size_t off = 0;
    char* ws = (char*)d_ws;
    auto take = [&](size_t nbytes) -> void* {
        void* p = ws + off;
        off = (off + nbytes + 255) & ~(size_t)255;
        return p;
    };
    float* bufA    = (float*)take((size_t)N * HD * 4);
    float* bufB    = (float*)take((size_t)N * HD * 4);
    float* dinv    = (float*)take((size_t)N * 4);
    int*   row_ptr = (int*)take((size_t)(N + 1) * 4);
    int*   cursor  = (int*)take((size_t)N * 4);
    int*   col     = (int*)take((size_t)E * 4);
    float* bn1p    = (float*)take(512 * 4);
    float* bn2p    = (float*)take(512 * 4);
    f16x8* BtF     = (f16x8*)take((size_t)(KPAD_IN / 8) * 256 * 16);  // 45056 chunks
    f16x8* Bt0     = (f16x8*)take((size_t)(HD / 8) * 256 * 16);       // 8192 chunks
    f16x8* Bt1     = (f16x8*)take((size_t)(HD / 8) * 256 * 16);
    size_t zwords = (size_t)N + 512 + 512 + (size_t)G * HD + G;
    unsigned int* zbase = (unsigned int*)take(zwords * 4);
    int*   counts = (int*)zbase;
    float* bn1s   = (float*)(zbase + N);
    float* bn2s   = bn1s + 512;
    float* pooled = bn2s + 512;
    float* cnt    = pooled + (size_t)G * HD;

    const int nchF = (KPAD_IN / 8) * 256;  // 45056
    const int nchH = (HD / 8) * 256;       // 8192

    // graph prep + weight pre-transposes
    zero_kernel<<<(int)((zwords + 255) / 256), 256, 0, stream>>>(zbase, (int)zwords);
    count_edges_kernel<<<(E + 255) / 256, 256, 0, stream>>>(dst, counts, E);
    scan_kernel<<<1, 1024, 0, stream>>>(counts, row_ptr, cursor, dinv, N);
    fill_edges_kernel<<<(E + 255) / 256, 256, 0, stream>>>(src, dst, cursor, col, E);
    btrans_kernel<<<(nchF + 255) / 256, 256, 0, stream>>>(fusion_W, BtF, DIM_IN, nchF);
    btrans_kernel<<<(nchH + 255) / 256, 256, 0, stream>>>(W0, Bt0, HD, nchH);
    btrans_kernel<<<(nchH + 255) / 256, 256, 0, stream>>>(W1, Bt1, HD, nchH);

    const int gblocks = (N + 127) / 128;
    // h0 = relu(concat @ fusion_W + b)
    fusion_mfma_kernel<<<gblocks, 512, 0, stream>>>(x, x_aug, BtF, fusion_b, bufA, N);
    // t1 = h0 @ W0
    hgemm_mfma_kernel<<<gblocks, 512, 0, stream>>>(bufA, Bt0, nullptr, bufB, N);
    // agg -> bufA (+b0)
    agg_kernel<<<N, 256, 0, stream>>>(bufB, dinv, row_ptr, col, b0, bufA, N);
    // BN1 stats
    bn_stats_kernel<<<(N + 255) / 256, 256, 0, stream>>>(bufA, bn1s, N);
    bn_final_kernel<<<1, 256, 0, stream>>>(bn1s, g0, be0, bn1p, N);
    // t2 = relu(bn1(bufA)) @ W1  (BN fused into A staging)
    hgemm_mfma_kernel<<<gblocks, 512, 0, stream>>>(bufA, Bt1, bn1p, bufB, N);
    // agg -> bufA (+b1)
    agg_kernel<<<N, 256, 0, stream>>>(bufB, dinv, row_ptr, col, b1, bufA, N);
    // BN2 stats
    bn_stats_kernel<<<(N + 255) / 256, 256, 0, stream>>>(bufA, bn2s, N);
    bn_final_kernel<<<1, 256, 0, stream>>>(bn2s, g1, be1, bn2p, N);
    // pooling + head
    graph_cnt_kernel<<<(N + 255) / 256, 256, 0, stream>>>(batch, cnt, N);
    bn_relu_pool_kernel<<<(N + 63) / 64, 256, 0, stream>>>(bufA, bn2p, batch, pooled, N);
    head_kernel<<<G, 64, 0, stream>>>(pooled, cnt, fc_W, fc_b, outp);
}

// Round 3
// 1002.149 us; speedup vs baseline: 3.8249x; 1.5460x over previous
//
#include <hip/hip_runtime.h>
#include <hip/hip_bf16.h>

#define N_NODES 100000
#define N_EDGES 1600000
#define N_GRAPH 1024
#define DIM_BASE 1000
#define DIM_AUG 384
#define DIM_IN 1384
#define KPAD_IN 1408
#define HD 256
#define BN_EPS 1e-5f

typedef _Float16 f16x8 __attribute__((ext_vector_type(8)));
typedef _Float16 f16x4 __attribute__((ext_vector_type(4)));
typedef float f32x4 __attribute__((ext_vector_type(4)));

// ---------------- utility ----------------
__global__ void zero_kernel(unsigned int* __restrict__ p, int n) {
    int i = blockIdx.x * blockDim.x + threadIdx.x;
    if (i < n) p[i] = 0u;
}

// ---------------- graph prep ----------------
__global__ void count_edges_kernel(const int* __restrict__ dst, int* __restrict__ counts, int e) {
    int i = blockIdx.x * blockDim.x + threadIdx.x;
    if (i < e) atomicAdd(&counts[dst[i]], 1);
}

// 98 blocks x 256 thr, 4 counts/thread -> per-block sums
__global__ __launch_bounds__(256) void deg_bsum_kernel(const int* __restrict__ counts,
                                                       int* __restrict__ bsum, int n) {
    __shared__ int sh[256];
    int t = threadIdx.x;
    int base = blockIdx.x * 1024 + t * 4;
    int s = 0;
    if (base < n) {  // n % 4 == 0 -> full int4
        int4 v = *(const int4*)&counts[base];
        s = v.x + v.y + v.z + v.w;
    }
    sh[t] = s;
    __syncthreads();
    for (int off = 128; off > 0; off >>= 1) {
        if (t < off) sh[t] += sh[t + off];
        __syncthreads();
    }
    if (t == 0) bsum[blockIdx.x] = sh[0];
}

// 1 block: exclusive scan of nb (<=128) block sums
__global__ __launch_bounds__(128) void scan_bsum_kernel(const int* __restrict__ bsum,
                                                        int* __restrict__ boff, int nb) {
    __shared__ int sh[128];
    int t = threadIdx.x;
    int v = (t < nb) ? bsum[t] : 0;
    sh[t] = v;
    __syncthreads();
    for (int off = 1; off < 128; off <<= 1) {
        int u = (t >= off) ? sh[t - off] : 0;
        __syncthreads();
        sh[t] += u;
        __syncthreads();
    }
    if (t < nb) boff[t] = sh[t] - v;
}

// 98 blocks x 256 thr: emit row_ptr / cursor / dinv
__global__ __launch_bounds__(256) void emit_csr_kernel(const int* __restrict__ counts,
                                                       const int* __restrict__ boff,
                                                       int* __restrict__ row_ptr,
                                                       int* __restrict__ cursor,
                                                       float* __restrict__ dinv, int n, int etot) {
    __shared__ int sh[256];
    int t = threadIdx.x;
    int base = blockIdx.x * 1024 + t * 4;
    int c0 = 0, c1 = 0, c2 = 0, c3 = 0;
    if (base < n) {
        int4 v = *(const int4*)&counts[base];
        c0 = v.x; c1 = v.y; c2 = v.z; c3 = v.w;
    }
    int s = c0 + c1 + c2 + c3;
    sh[t] = s;
    __syncthreads();
    for (int off = 1; off < 256; off <<= 1) {
        int u = (t >= off) ? sh[t - off] : 0;
        __syncthreads();
        sh[t] += u;
        __syncthreads();
    }
    if (base < n) {
        int run = boff[blockIdx.x] + sh[t] - s;
        int4 rp;
        rp.x = run; run += c0;
        rp.y = run; run += c1;
        rp.z = run; run += c2;
        rp.w = run;
        *(int4*)&row_ptr[base] = rp;
        *(int4*)&cursor[base] = rp;
        float4 dv;
        dv.x = rsqrtf((float)c0 + 1.0f);
        dv.y = rsqrtf((float)c1 + 1.0f);
        dv.z = rsqrtf((float)c2 + 1.0f);
        dv.w = rsqrtf((float)c3 + 1.0f);
        *(float4*)&dinv[base] = dv;
    }
    if (blockIdx.x == 0 && t == 0) row_ptr[n] = etot;
}

__global__ void fill_edges_kernel(const int* __restrict__ src, const int* __restrict__ dst,
                                  int* __restrict__ cursor, int* __restrict__ col, int e) {
    int i = blockIdx.x * blockDim.x + threadIdx.x;
    if (i < e) {
        int pos = atomicAdd(&cursor[dst[i]], 1);
        col[pos] = src[i];
    }
}

// ---------------- B pre-transpose to fragment-ready f16 chunks ----------------
__global__ __launch_bounds__(256) void btrans_kernel(const float* __restrict__ W,
                                                     f16x8* __restrict__ Bt,
                                                     int K, int nchunks) {
    int idx = blockIdx.x * 256 + threadIdx.x;
    if (idx >= nchunks) return;
    int col = idx & 255;
    int kbase = (idx >> 8) * 8;
    f16x8 h;
#pragma unroll
    for (int j = 0; j < 8; ++j) {
        int k = kbase + j;
        float v = (k < K) ? W[(size_t)k * HD + col] : 0.f;
        h[j] = (_Float16)v;
    }
    Bt[idx] = h;
}

// ---------------- fusion GEMM (MFMA): h0 = relu(concat(x,xa) @ W + bias), f16 out ----------------
__global__ __launch_bounds__(512, 4) void fusion_mfma_kernel(
        const float* __restrict__ x, const float* __restrict__ xa,
        const f16x8* __restrict__ Bt, const float* __restrict__ bias,
        _Float16* __restrict__ C, int M) {
    __shared__ _Float16 Al[128 * 40];
    __shared__ _Float16 Bl[32 * 256];
    int tid = threadIdx.x;
    int lane = tid & 63;
    int wid = tid >> 6;
    int wr = wid >> 2, wc = wid & 3;
    int l16 = lane & 15, l4 = lane >> 4;
    int row0 = blockIdx.x * 128;

    f32x4 acc[4][4];
#pragma unroll
    for (int m = 0; m < 4; ++m)
#pragma unroll
        for (int n = 0; n < 4; ++n) acc[m][n] = (f32x4){0.f, 0.f, 0.f, 0.f};

    int arow = tid >> 2;
    int akq = (tid & 3) * 8;
    int ar = row0 + arow;

    const int S = KPAD_IN / 32;  // 44
    for (int s = 0; s < S; ++s) {
        int kg = s * 32 + akq;
        float fv[8];
#pragma unroll
        for (int j = 0; j < 8; ++j) fv[j] = 0.f;
        if (ar < M && kg < DIM_IN) {
            const float* sp = (kg < DIM_BASE) ? (x + (size_t)ar * DIM_BASE + kg)
                                              : (xa + (size_t)ar * DIM_AUG + (kg - DIM_BASE));
            float4 v0 = ((const float4*)sp)[0];
            float4 v1 = ((const float4*)sp)[1];
            fv[0] = v0.x; fv[1] = v0.y; fv[2] = v0.z; fv[3] = v0.w;
            fv[4] = v1.x; fv[5] = v1.y; fv[6] = v1.z; fv[7] = v1.w;
        }
        f16x8 av;
#pragma unroll
        for (int j = 0; j < 8; ++j) av[j] = (_Float16)fv[j];
        f16x8 bv0 = Bt[(size_t)s * 1024 + tid];
        f16x8 bv1 = Bt[(size_t)s * 1024 + 512 + tid];

        __syncthreads();
        *(f16x8*)&Al[arow * 40 + akq] = av;
        *(f16x8*)&Bl[(size_t)tid * 8] = bv0;
        *(f16x8*)&Bl[(size_t)(512 + tid) * 8] = bv1;
        __syncthreads();

        f16x8 bf[4];
#pragma unroll
        for (int n = 0; n < 4; ++n)
            bf[n] = *(const f16x8*)&Bl[(size_t)(l4 * 256 + wc * 64 + n * 16 + l16) * 8];
#pragma unroll
        for (int m = 0; m < 4; ++m) {
            f16x8 af = *(const f16x8*)&Al[(size_t)(wr * 64 + m * 16 + l16) * 40 + l4 * 8];
#pragma unroll
            for (int n = 0; n < 4; ++n)
                acc[m][n] = __builtin_amdgcn_mfma_f32_16x16x32_f16(af, bf[n], acc[m][n], 0, 0, 0);
        }
    }

#pragma unroll
    for (int n = 0; n < 4; ++n) {
        int colF = wc * 64 + n * 16 + l16;
        float bcol = bias[colF];
#pragma unroll
        for (int m = 0; m < 4; ++m) {
#pragma unroll
            for (int r = 0; r < 4; ++r) {
                int rowF = row0 + wr * 64 + m * 16 + l4 * 4 + r;
                if (rowF < M)
                    C[(size_t)rowF * HD + colF] = (_Float16)fmaxf(acc[m][n][r] + bcol, 0.f);
            }
        }
    }
}

// ---------------- H-GEMM, f16 A (no BN): t = A @ W, f16 out ----------------
__global__ __launch_bounds__(512, 4) void hgemm_f16_kernel(
        const _Float16* __restrict__ A, const f16x8* __restrict__ Bt,
        _Float16* __restrict__ C, int M) {
    __shared__ _Float16 Al[128 * 40];
    __shared__ _Float16 Bl[32 * 256];
    int tid = threadIdx.x;
    int lane = tid & 63;
    int wid = tid >> 6;
    int wr = wid >> 2, wc = wid & 3;
    int l16 = lane & 15, l4 = lane >> 4;
    int row0 = blockIdx.x * 128;

    f32x4 acc[4][4];
#pragma unroll
    for (int m = 0; m < 4; ++m)
#pragma unroll
        for (int n = 0; n < 4; ++n) acc[m][n] = (f32x4){0.f, 0.f, 0.f, 0.f};

    int arow = tid >> 2;
    int akq = (tid & 3) * 8;
    int ar = row0 + arow;

    const int S = HD / 32;  // 8
    for (int s = 0; s < S; ++s) {
        int kg = s * 32 + akq;
        f16x8 av = (f16x8)(_Float16)0;
        if (ar < M) av = *(const f16x8*)&A[(size_t)ar * HD + kg];
        f16x8 bv0 = Bt[(size_t)s * 1024 + tid];
        f16x8 bv1 = Bt[(size_t)s * 1024 + 512 + tid];

        __syncthreads();
        *(f16x8*)&Al[arow * 40 + akq] = av;
        *(f16x8*)&Bl[(size_t)tid * 8] = bv0;
        *(f16x8*)&Bl[(size_t)(512 + tid) * 8] = bv1;
        __syncthreads();

        f16x8 bf[4];
#pragma unroll
        for (int n = 0; n < 4; ++n)
            bf[n] = *(const f16x8*)&Bl[(size_t)(l4 * 256 + wc * 64 + n * 16 + l16) * 8];
#pragma unroll
        for (int m = 0; m < 4; ++m) {
            f16x8 af = *(const f16x8*)&Al[(size_t)(wr * 64 + m * 16 + l16) * 40 + l4 * 8];
#pragma unroll
            for (int n = 0; n < 4; ++n)
                acc[m][n] = __builtin_amdgcn_mfma_f32_16x16x32_f16(af, bf[n], acc[m][n], 0, 0, 0);
        }
    }

#pragma unroll
    for (int n = 0; n < 4; ++n) {
        int colF = wc * 64 + n * 16 + l16;
#pragma unroll
        for (int m = 0; m < 4; ++m) {
#pragma unroll
            for (int r = 0; r < 4; ++r) {
                int rowF = row0 + wr * 64 + m * 16 + l4 * 4 + r;
                if (rowF < M)
                    C[(size_t)rowF * HD + colF] = (_Float16)acc[m][n][r];
            }
        }
    }
}

// ---------------- H-GEMM, fp32 A with fused BN+ReLU: t = relu(A*sc+sh) @ W, f16 out ----------------
__global__ __launch_bounds__(512, 4) void hgemm_bn_kernel(
        const float* __restrict__ A, const f16x8* __restrict__ Bt,
        const float* __restrict__ bnp, _Float16* __restrict__ C, int M) {
    __shared__ _Float16 Al[128 * 40];
    __shared__ _Float16 Bl[32 * 256];
    __shared__ float bns[512];
    int tid = threadIdx.x;
    int lane = tid & 63;
    int wid = tid >> 6;
    int wr = wid >> 2, wc = wid & 3;
    int l16 = lane & 15, l4 = lane >> 4;
    int row0 = blockIdx.x * 128;

    bns[tid] = bnp[tid & 511];

    f32x4 acc[4][4];
#pragma unroll
    for (int m = 0; m < 4; ++m)
#pragma unroll
        for (int n = 0; n < 4; ++n) acc[m][n] = (f32x4){0.f, 0.f, 0.f, 0.f};

    int arow = tid >> 2;
    int akq = (tid & 3) * 8;
    int ar = row0 + arow;

    __syncthreads();  // bns visible

    const int S = HD / 32;
    for (int s = 0; s < S; ++s) {
        int kg = s * 32 + akq;
        float fv[8];
#pragma unroll
        for (int j = 0; j < 8; ++j) fv[j] = 0.f;
        if (ar < M) {
            const float* sp = A + (size_t)ar * HD + kg;
            float4 v0 = ((const float4*)sp)[0];
            float4 v1 = ((const float4*)sp)[1];
            fv[0] = v0.x; fv[1] = v0.y; fv[2] = v0.z; fv[3] = v0.w;
            fv[4] = v1.x; fv[5] = v1.y; fv[6] = v1.z; fv[7] = v1.w;
        }
        f16x8 av;
#pragma unroll
        for (int j = 0; j < 8; ++j)
            av[j] = (_Float16)fmaxf(fmaf(fv[j], bns[kg + j], bns[HD + kg + j]), 0.f);
        f16x8 bv0 = Bt[(size_t)s * 1024 + tid];
        f16x8 bv1 = Bt[(size_t)s * 1024 + 512 + tid];

        __syncthreads();
        *(f16x8*)&Al[arow * 40 + akq] = av;
        *(f16x8*)&Bl[(size_t)tid * 8] = bv0;
        *(f16x8*)&Bl[(size_t)(512 + tid) * 8] = bv1;
        __syncthreads();

        f16x8 bf[4];
#pragma unroll
        for (int n = 0; n < 4; ++n)
            bf[n] = *(const f16x8*)&Bl[(size_t)(l4 * 256 + wc * 64 + n * 16 + l16) * 8];
#pragma unroll
        for (int m = 0; m < 4; ++m) {
            f16x8 af = *(const f16x8*)&Al[(size_t)(wr * 64 + m * 16 + l16) * 40 + l4 * 8];
#pragma unroll
            for (int n = 0; n < 4; ++n)
                acc[m][n] = __builtin_amdgcn_mfma_f32_16x16x32_f16(af, bf[n], acc[m][n], 0, 0, 0);
        }
    }

#pragma unroll
    for (int n = 0; n < 4; ++n) {
        int colF = wc * 64 + n * 16 + l16;
#pragma unroll
        for (int m = 0; m < 4; ++m) {
#pragma unroll
            for (int r = 0; r < 4; ++r) {
                int rowF = row0 + wr * 64 + m * 16 + l4 * 4 + r;
                if (rowF < M)
                    C[(size_t)rowF * HD + colF] = (_Float16)acc[m][n][r];
            }
        }
    }
}

// ---------------- GCN aggregation: wave-per-node, f16 gather, fp32 out ----------------
__global__ __launch_bounds__(256) void agg_kernel(
        const _Float16* __restrict__ t, const float* __restrict__ dinv,
        const int* __restrict__ row_ptr, const int* __restrict__ col,
        const float* __restrict__ bias, float* __restrict__ outp, int n) {
    int wid = threadIdx.x >> 6;
    int lane = threadIdx.x & 63;
    int i = blockIdx.x * 4 + wid;
    if (i >= n) return;
    int c0 = lane * 4;
    float di = dinv[i];
    float di2 = di * di;
    f16x4 sv = *(const f16x4*)&t[(size_t)i * HD + c0];
    float a0 = (float)sv[0] * di2, a1 = (float)sv[1] * di2;
    float a2 = (float)sv[2] * di2, a3 = (float)sv[3] * di2;
    int e = row_ptr[i], end = row_ptr[i + 1];
    for (; e + 1 < end; e += 2) {
        int s0 = col[e], s1 = col[e + 1];
        float w0 = dinv[s0] * di, w1 = dinv[s1] * di;
        f16x4 v0 = *(const f16x4*)&t[(size_t)s0 * HD + c0];
        f16x4 v1 = *(const f16x4*)&t[(size_t)s1 * HD + c0];
        a0 = fmaf((float)v0[0], w0, a0); a1 = fmaf((float)v0[1], w0, a1);
        a2 = fmaf((float)v0[2], w0, a2); a3 = fmaf((float)v0[3], w0, a3);
        a0 = fmaf((float)v1[0], w1, a0); a1 = fmaf((float)v1[1], w1, a1);
        a2 = fmaf((float)v1[2], w1, a2); a3 = fmaf((float)v1[3], w1, a3);
    }
    if (e < end) {
        int s0 = col[e];
        float w0 = dinv[s0] * di;
        f16x4 v0 = *(const f16x4*)&t[(size_t)s0 * HD + c0];
        a0 = fmaf((float)v0[0], w0, a0); a1 = fmaf((float)v0[1], w0, a1);
        a2 = fmaf((float)v0[2], w0, a2); a3 = fmaf((float)v0[3], w0, a3);
    }
    float4 b = *(const float4*)&bias[c0];
    float4 o;
    o.x = a0 + b.x; o.y = a1 + b.y; o.z = a2 + b.z; o.w = a3 + b.w;
    *(float4*)&outp[(size_t)i * HD + c0] = o;
}

// ---------------- BatchNorm stats ----------------
__global__ __launch_bounds__(256) void bn_stats_kernel(const float* __restrict__ a,
                                                       float* __restrict__ sums, int n) {
    int tid = threadIdx.x;
    int r0 = blockIdx.x * 256;
    int r1 = min(r0 + 256, n);
    float s = 0.f, s2 = 0.f;
    for (int r = r0; r < r1; ++r) {
        float v = a[(size_t)r * HD + tid];
        s += v;
        s2 = fmaf(v, v, s2);
    }
    atomicAdd(&sums[tid], s);
    atomicAdd(&sums[HD + tid], s2);
}

__global__ __launch_bounds__(256) void bn_final_kernel(const float* __restrict__ sums,
                                                       const float* __restrict__ g,
                                                       const float* __restrict__ be,
                                                       float* __restrict__ p, int n) {
    int tid = threadIdx.x;
    float mean = sums[tid] / (float)n;
    float var = sums[HD + tid] / (float)n - mean * mean;
    float sc = g[tid] * rsqrtf(var + BN_EPS);
    p[tid] = sc;
    p[HD + tid] = be[tid] - mean * sc;
}

// ---------------- graph sizes ----------------
__global__ void graph_cnt_kernel(const int* __restrict__ batch, float* __restrict__ cnt, int n) {
    int i = blockIdx.x * blockDim.x + threadIdx.x;
    if (i < n) atomicAdd(&cnt[batch[i]], 1.0f);
}

// ---------------- BN2 apply + relu + mean-pool accumulate (batch sorted) ----------------
__global__ __launch_bounds__(256) void bn_relu_pool_kernel(const float* __restrict__ a,
                                                           const float* __restrict__ p,
                                                           const int* __restrict__ batch,
                                                           float* __restrict__ pooled, int n) {
    int tid = threadIdx.x;
    int n0 = blockIdx.x * 64;
    int n1 = min(n0 + 64, n);
    if (n0 >= n) return;
    float sc = p[tid], sh = p[HD + tid];
    int curg = batch[n0];
    float acc = 0.f;
    for (int i = n0; i < n1; ++i) {
        int g = batch[i];
        if (g != curg) {
            atomicAdd(&pooled[(size_t)curg * HD + tid], acc);
            acc = 0.f;
            curg = g;
        }
        acc += fmaxf(fmaf(a[(size_t)i * HD + tid], sc, sh), 0.f);
    }
    atomicAdd(&pooled[(size_t)curg * HD + tid], acc);
}

// ---------------- head ----------------
__global__ __launch_bounds__(64) void head_kernel(const float* __restrict__ pooled,
                                                  const float* __restrict__ cnt,
                                                  const float* __restrict__ fcW,
                                                  const float* __restrict__ fcb,
                                                  float* __restrict__ outp) {
    int g = blockIdx.x, lane = threadIdx.x;
    float inv = 1.0f / fmaxf(cnt[g], 1.0f);
    float a0 = 0.f, a1 = 0.f;
    for (int j = lane; j < HD; j += 64) {
        float v = pooled[(size_t)g * HD + j] * inv;
        a0 = fmaf(v, fcW[j * 2 + 0], a0);
        a1 = fmaf(v, fcW[j * 2 + 1], a1);
    }
    for (int off = 32; off > 0; off >>= 1) {
        a0 += __shfl_down(a0, off);
        a1 += __shfl_down(a1, off);
    }
    if (lane == 0) {
        float l0 = a0 + fcb[0], l1 = a1 + fcb[1];
        float m = fmaxf(l0, l1);
        float lse = m + logf(expf(l0 - m) + expf(l1 - m));
        outp[g * 2 + 0] = l0 - lse;
        outp[g * 2 + 1] = l1 - lse;
    }
}

extern "C" void kernel_launch(void* const* d_in, const int* in_sizes, int n_in,
                              void* d_out, int out_size, void* d_ws, size_t ws_size,
                              hipStream_t stream) {
    const float* x        = (const float*)d_in[0];
    const float* x_aug    = (const float*)d_in[1];
    const float* fusion_W = (const float*)d_in[2];
    const float* fusion_b = (const float*)d_in[3];
    const float* W0       = (const float*)d_in[4];
    const float* b0       = (const float*)d_in[5];
    const float* g0       = (const float*)d_in[6];
    const float* be0      = (const float*)d_in[7];
    const float* W1       = (const float*)d_in[8];
    const float* b1       = (const float*)d_in[9];
    const float* g1       = (const float*)d_in[10];
    const float* be1      = (const float*)d_in[11];
    const float* fc_W     = (const float*)d_in[12];
    const float* fc_b     = (const float*)d_in[13];
    const int*   eidx     = (const int*)d_in[14];
    const int*   batch    = (const int*)d_in[15];
    float* outp = (float*)d_out;

    const int N = N_NODES, E = N_EDGES, G = N_GRAPH;
    const int* src = eidx;
    const int* dst = eidx + E;

    size_t off = 0;
    char* ws = (char*)d_ws;
    auto take = [&](size_t nbytes) -> void* {
        void* p = ws + off;
        off = (off + nbytes + 255) & ~(size_t)255;
        return p;
    };
    float*     bufA    = (float*)take((size_t)N * HD * 4);      // agg outputs (fp32)
    _Float16*  bufH    = (_Float16*)take((size_t)N * HD * 2);   // h0 (f16)
    _Float16*  bufT    = (_Float16*)take((size_t)N * HD * 2);   // t1/t2 (f16)
    float*     dinv    = (float*)take((size_t)N * 4);
    int*       row_ptr = (int*)take((size_t)(N + 1) * 4);
    int*       cursor  = (int*)take((size_t)N * 4);
    int*       col     = (int*)take((size_t)E * 4);
    float*     bn1p    = (float*)take(512 * 4);
    float*     bn2p    = (float*)take(512 * 4);
    int*       bsum    = (int*)take(128 * 4);
    int*       boff    = (int*)take(128 * 4);
    f16x8*     BtF     = (f16x8*)take((size_t)(KPAD_IN / 8) * 256 * 16);
    f16x8*     Bt0     = (f16x8*)take((size_t)(HD / 8) * 256 * 16);
    f16x8*     Bt1     = (f16x8*)take((size_t)(HD / 8) * 256 * 16);
    size_t zwords = (size_t)N + 512 + 512 + (size_t)G * HD + G;
    unsigned int* zbase = (unsigned int*)take(zwords * 4);
    int*   counts = (int*)zbase;
    float* bn1s   = (float*)(zbase + N);
    float* bn2s   = bn1s + 512;
    float* pooled = bn2s + 512;
    float* cnt    = pooled + (size_t)G * HD;

    const int nchF = (KPAD_IN / 8) * 256;
    const int nchH = (HD / 8) * 256;
    const int nScanB = (N + 1023) / 1024;  // 98

    // graph prep + weight pre-transposes
    zero_kernel<<<(int)((zwords + 255) / 256), 256, 0, stream>>>(zbase, (int)zwords);
    count_edges_kernel<<<(E + 255) / 256, 256, 0, stream>>>(dst, counts, E);
    deg_bsum_kernel<<<nScanB, 256, 0, stream>>>(counts, bsum, N);
    scan_bsum_kernel<<<1, 128, 0, stream>>>(bsum, boff, nScanB);
    emit_csr_kernel<<<nScanB, 256, 0, stream>>>(counts, boff, row_ptr, cursor, dinv, N, E);
    fill_edges_kernel<<<(E + 255) / 256, 256, 0, stream>>>(src, dst, cursor, col, E);
    btrans_kernel<<<(nchF + 255) / 256, 256, 0, stream>>>(fusion_W, BtF, DIM_IN, nchF);
    btrans_kernel<<<(nchH + 255) / 256, 256, 0, stream>>>(W0, Bt0, HD, nchH);
    btrans_kernel<<<(nchH + 255) / 256, 256, 0, stream>>>(W1, Bt1, HD, nchH);

    const int gblocks = (N + 127) / 128;
    // h0 = relu(concat @ fusion_W + b)  (f16)
    fusion_mfma_kernel<<<gblocks, 512, 0, stream>>>(x, x_aug, BtF, fusion_b, bufH, N);
    // t1 = h0 @ W0  (f16)
    hgemm_f16_kernel<<<gblocks, 512, 0, stream>>>(bufH, Bt0, bufT, N);
    // agg -> bufA (+b0), fp32
    agg_kernel<<<(N + 3) / 4, 256, 0, stream>>>(bufT, dinv, row_ptr, col, b0, bufA, N);
    // BN1
    bn_stats_kernel<<<(N + 255) / 256, 256, 0, stream>>>(bufA, bn1s, N);
    bn_final_kernel<<<1, 256, 0, stream>>>(bn1s, g0, be0, bn1p, N);
    // t2 = relu(bn1(bufA)) @ W1  (f16)
    hgemm_bn_kernel<<<gblocks, 512, 0, stream>>>(bufA, Bt1, bn1p, bufT, N);
    // agg -> bufA (+b1)
    agg_kernel<<<(N + 3) / 4, 256, 0, stream>>>(bufT, dinv, row_ptr, col, b1, bufA, N);
    // BN2
    bn_stats_kernel<<<(N + 255) / 256, 256, 0, stream>>>(bufA, bn2s, N);
    bn_final_kernel<<<1, 256, 0, stream>>>(bn2s, g1, be1, bn2p, N);
    // pooling + head
    graph_cnt_kernel<<<(N + 255) / 256, 256, 0, stream>>>(batch, cnt, N);
    bn_relu_pool_kernel<<<(N + 63) / 64, 256, 0, stream>>>(bufA, bn2p, batch, pooled, N);
    head_kernel<<<G, 64, 0, stream>>>(pooled, cnt, fc_W, fc_b, outp);
}